// Round 6
// baseline (369.774 us; speedup 1.0000x reference)
//
#include <hip/hip_runtime.h>
#include <stdint.h>

#define BSZ 2
#define TT 2048
#define DD 1024
#define HH 16
#define HD 64

typedef __bf16 bf16x8 __attribute__((ext_vector_type(8)));
typedef float f32x4 __attribute__((ext_vector_type(4)));

// fast exp2: single v_exp_f32 (builtin if available, else inline asm + hazard nop)
#if __has_builtin(__builtin_amdgcn_exp2f)
__device__ __forceinline__ float fexp2(float x) { return __builtin_amdgcn_exp2f(x); }
#else
__device__ __forceinline__ float fexp2(float x) {
    float r; asm("v_exp_f32 %0, %1\n\ts_nop 1" : "=v"(r) : "v"(x)); return r;
}
#endif

__device__ __forceinline__ unsigned short f2bf(float f) {
    union { float f; unsigned u; } c; c.f = f;
    unsigned u = c.u;
    unsigned r = u + 0x7fffu + ((u >> 16) & 1u);
    return (unsigned short)(r >> 16);
}
__device__ __forceinline__ unsigned fasu(float f) {
    union { float f; unsigned u; } c; c.f = f; return c.u;
}

union U4BF { uint4 u; bf16x8 b; };
__device__ __forceinline__ bf16x8 as_bf8(uint4 v) { U4BF c; c.u = v; return c.b; }

// ---- async global->LDS, 16B per lane; LDS dst = wave-uniform base + lane*16 ----
#if __has_builtin(__builtin_amdgcn_global_load_lds)
__device__ __forceinline__ void gl_lds16(const ushort* g, ushort* l) {
    __builtin_amdgcn_global_load_lds(
        (const __attribute__((address_space(1))) uint32_t*)g,
        (__attribute__((address_space(3))) uint32_t*)l, 16, 0, 0);
}
#define GLL_LANE 1
#else
__device__ __forceinline__ void gl_lds16_fallback(const ushort* g, ushort* l, int lane) {
    *(uint4*)(l + lane * 8) = *(const uint4*)(g);
}
#define GLL_LANE 0
#endif

// ---------------- prep: y<3 -> fp32->bf16 cvt of q/k/v ; y==3 -> W transpose ----
__global__ __launch_bounds__(256)
void prep(const float* __restrict__ q, const float* __restrict__ k,
          const float* __restrict__ v,
          const float* __restrict__ W0, const float* __restrict__ W1,
          const float* __restrict__ W2, const float* __restrict__ W3,
          ushort* __restrict__ xq, ushort* __restrict__ xk, ushort* __restrict__ xv,
          ushort* __restrict__ T0, ushort* __restrict__ T1,
          ushort* __restrict__ T2, ushort* __restrict__ T3) {
    __shared__ float sh[32][33];
    const int y = blockIdx.y;
    if (y < 3) {
        const float* in = (y == 0) ? q : (y == 1) ? k : v;
        ushort* out = (y == 0) ? xq : (y == 1) ? xk : xv;
        int i = blockIdx.x * 256 + threadIdx.x;
        float4 val = ((const float4*)in)[i];
        ushort4 o;
        o.x = f2bf(val.x); o.y = f2bf(val.y); o.z = f2bf(val.z); o.w = f2bf(val.w);
        ((ushort4*)out)[i] = o;
    } else {
        const int x = blockIdx.x;
        const float* src; ushort* dst;
        switch (x >> 10) {
            case 0:  src = W0; dst = T0; break;
            case 1:  src = W1; dst = T1; break;
            case 2:  src = W2; dst = T2; break;
            default: src = W3; dst = T3; break;
        }
        const int tile = x & 1023;
        const int k0 = (tile >> 5) * 32, n0 = (tile & 31) * 32;
        const int tx = threadIdx.x & 31, ty = threadIdx.x >> 5;  // ty 0..7
        #pragma unroll
        for (int p = 0; p < 4; ++p)
            sh[ty + 8 * p][tx] = src[(size_t)(k0 + ty + 8 * p) * DD + n0 + tx];
        __syncthreads();
        #pragma unroll
        for (int p = 0; p < 4; ++p)
            dst[(size_t)(n0 + ty + 8 * p) * DD + k0 + tx] = f2bf(sh[tx][ty + 8 * p]);
    }
}

// ---------------- V transpose: Vt[bh][d][t] = Vh[bh][t][d] ----------------
__global__ __launch_bounds__(256)
void vtrans(const ushort* __restrict__ Vh, ushort* __restrict__ Vt) {
    __shared__ ushort sh[64][72];
    const int tid = threadIdx.x;
    const int bh = blockIdx.y;
    const int t0 = blockIdx.x * 64;
    const size_t base = (size_t)bh * (TT * HD);
    #pragma unroll
    for (int it = 0; it < 2; ++it) {
        int u = tid + it * 256;
        int r = u >> 3, c8 = (u & 7) * 8;
        *(uint4*)&sh[r][c8] = *(const uint4*)(Vh + base + (size_t)(t0 + r) * HD + c8);
    }
    __syncthreads();
    #pragma unroll
    for (int it = 0; it < 2; ++it) {
        int u = tid + it * 256;
        int d = u >> 3, c8 = (u & 7) * 8;
        alignas(16) ushort tmp[8];
        #pragma unroll
        for (int p = 0; p < 8; ++p) tmp[p] = sh[c8 + p][d];
        *(uint4*)(Vt + base + (size_t)d * TT + t0 + c8) = *(const uint4*)tmp;
    }
}

// ---------------- BMx128 bf16 MFMA GEMM with global_load_lds staging ----------------
// OUT_MODE 0: z-batched QKV, bf16 out [bh][t][d]. OUT_MODE 1: fp32 out [4096][1024].
template<int BM, int OUT_MODE>
__global__ __launch_bounds__(256)
void gemm_mfma(const ushort* __restrict__ A0, const ushort* __restrict__ B0,
               const float* __restrict__ c0, void* __restrict__ d0,
               const ushort* __restrict__ A1, const ushort* __restrict__ B1,
               const float* __restrict__ c1, void* __restrict__ d1,
               const ushort* __restrict__ A2, const ushort* __restrict__ B2,
               const float* __restrict__ c2, void* __restrict__ d2) {
    constexpr int TI = 4;
    constexpr int TJ = (BM == 128) ? 4 : 2;
    constexpr int WC = (BM == 128) ? 2 : 4;
    __shared__ __attribute__((aligned(16))) ushort As[BM][32];
    __shared__ __attribute__((aligned(16))) ushort Bs[128][32];
    const ushort* A; const ushort* Bt; const float* bias; void* outp;
    switch (blockIdx.z) {
        case 0:  A = A0; Bt = B0; bias = c0; outp = d0; break;
        case 1:  A = A1; Bt = B1; bias = c1; outp = d1; break;
        default: A = A2; Bt = B2; bias = c2; outp = d2; break;
    }
    const int tid  = threadIdx.x;
    const int lane = tid & 63, w = tid >> 6;
    const int wr = w / WC, wc = w % WC;
    const int ln = lane & 15, quad = lane >> 4;
    const int m0 = blockIdx.y * BM, n0 = blockIdx.x * 128;

    const f32x4 zero = {0.f, 0.f, 0.f, 0.f};
    f32x4 acc[TI][TJ];
    #pragma unroll
    for (int i = 0; i < TI; ++i)
        #pragma unroll
        for (int j = 0; j < TJ; ++j) acc[i][j] = zero;

    const int lr  = lane >> 2;        // row within 16-row stripe
    const int lc8 = (lane & 3) * 8;   // 0,8,16,24

    for (int kb = 0; kb < 1024; kb += 32) {
        #pragma unroll
        for (int it = 0; it < BM / 64; ++it) {
            int r0 = it * 64 + w * 16;
#if GLL_LANE
            gl_lds16(A + (size_t)(m0 + r0 + lr) * 1024 + kb + lc8, &As[r0][0]);
#else
            gl_lds16_fallback(A + (size_t)(m0 + r0 + lr) * 1024 + kb + lc8, &As[r0][0], lane);
#endif
        }
        #pragma unroll
        for (int it = 0; it < 2; ++it) {
            int r0 = it * 64 + w * 16;
#if GLL_LANE
            gl_lds16(Bt + (size_t)(n0 + r0 + lr) * 1024 + kb + lc8, &Bs[r0][0]);
#else
            gl_lds16_fallback(Bt + (size_t)(n0 + r0 + lr) * 1024 + kb + lc8, &Bs[r0][0], lane);
#endif
        }
        __syncthreads();
        bf16x8 af[TI], bfr[TJ];
        #pragma unroll
        for (int i = 0; i < TI; ++i)
            af[i] = as_bf8(*(const uint4*)&As[wr * 64 + i * 16 + ln][quad * 8]);
        #pragma unroll
        for (int j = 0; j < TJ; ++j)
            bfr[j] = as_bf8(*(const uint4*)&Bs[wc * (TJ * 16) + j * 16 + ln][quad * 8]);
        #pragma unroll
        for (int i = 0; i < TI; ++i)
            #pragma unroll
            for (int j = 0; j < TJ; ++j)
                acc[i][j] = __builtin_amdgcn_mfma_f32_16x16x32_bf16(af[i], bfr[j], acc[i][j], 0, 0, 0);
        __syncthreads();
    }

    #pragma unroll
    for (int j = 0; j < TJ; ++j) {
        int n = n0 + wc * (TJ * 16) + j * 16 + ln;
        float bv = bias[n];
        #pragma unroll
        for (int i = 0; i < TI; ++i) {
            #pragma unroll
            for (int r = 0; r < 4; ++r) {
                int m = m0 + wr * 64 + i * 16 + quad * 4 + r;
                float v = acc[i][j][r] + bv;
                if (OUT_MODE == 0) {
                    int b = m >> 11, t = m & 2047, h = n >> 6, d = n & 63;
                    ((ushort*)outp)[(((size_t)(b * HH + h)) * TT + t) * HD + d] = f2bf(v);
                } else {
                    ((float*)outp)[(size_t)m * 1024 + n] = v;
                }
            }
        }
    }
}

// ---------------- flash attention: persistent folded, single-phase merge ----------
// 1024 blocks; block p runs items p and 2047-p (heavy-first sorted).
// Item = (b,h,32 q-rows); 4 waves k-split; one-shot LDS merge.
// Qh,Kh: [bh][t][d]   Vtg: [bh][d][t]   out: [B][T][D] bf16
__global__ __launch_bounds__(256, 4)
void attn_kernel(const ushort* __restrict__ Qh, const ushort* __restrict__ Kh,
                 const ushort* __restrict__ Vtg, ushort* __restrict__ outp) {
    // Ps: ushort[4][32][72]=18432B ; Rbuf: float[3][64][44]=33792B (overlaid)
    __shared__ __attribute__((aligned(16))) char smem[33792];
    ushort (*Ps)[32][72] = (ushort (*)[32][72])smem;
    float  (*Rbuf)[64][44] = (float (*)[64][44])smem;

    const int tid  = threadIdx.x;
    const int lane = tid & 63, w = tid >> 6;     // w = k-chunk index 0..3
    const int ln = lane & 15, quad = lane >> 4;

    bf16x8 ones;
    {
        union { ushort us[8]; bf16x8 v; } uu;
        #pragma unroll
        for (int p = 0; p < 8; ++p) uu.us[p] = 0x3F80;
        ones = uu.v;
    }
    const f32x4 zero = {0.f, 0.f, 0.f, 0.f};
    const float c1 = 0.125f * 1.44269504f;  // scale*log2e

    for (int sel = 0; sel < 2; ++sel) {
        __syncthreads();  // Rbuf reads (prev item) done before Ps reuse
        const int item = sel ? (2047 - (int)blockIdx.x) : (int)blockIdx.x;
        const int h = 15 - (item >> 7);
        const int rr = item & 127;
        const int b = rr & 1;
        const int qt = rr >> 1;
        const int bh = b * 16 + h;
        const int qbase = qt * 32;
        const float slope2 = exp2f(-0.5f * (float)(h + 1)) * 1.44269504f;
        const size_t base = (size_t)bh * (TT * HD);

        // ALiBi band: tiles with slope2*dist >= 18 contribute < ~2^-11 of mass
        const int D = (int)ceilf(18.0f / slope2);
        int lo = qbase - D;
        int kt_lo = (lo > 0) ? (lo >> 6) : 0;
        int kt_hi = (qbase + 32 + D + 63) >> 6;
        if (kt_hi > TT / 64) kt_hi = TT / 64;
        const int nt = kt_hi - kt_lo;
        const int cs = (nt + 3) >> 2;
        const int my_lo = kt_lo + w * cs;
        const int my_hi = (my_lo + cs < kt_hi) ? (my_lo + cs) : kt_hi;

        // Q fragments (A-layout)
        bf16x8 qa[2][2];
        #pragma unroll
        for (int g = 0; g < 2; ++g) {
            const uint4* qp = (const uint4*)(Qh + base + (size_t)(qbase + g * 16 + ln) * HD);
            qa[g][0] = as_bf8(qp[quad]);
            qa[g][1] = as_bf8(qp[4 + quad]);
        }
        f32x4 o[2][4], lsum[2];
        #pragma unroll
        for (int g = 0; g < 2; ++g) {
            lsum[g] = zero;
            #pragma unroll
            for (int dn = 0; dn < 4; ++dn) o[g][dn] = zero;
        }
        float qrf[2][4];
        #pragma unroll
        for (int g = 0; g < 2; ++g)
            #pragma unroll
            for (int r = 0; r < 4; ++r)
                qrf[g][r] = (float)(qbase + g * 16 + quad * 4 + r);

        const ushort* kp = Kh  + base + (size_t)ln * HD + quad * 8;
        const ushort* vp = Vtg + base + (size_t)ln * TT + quad * 8;

        if (my_lo < my_hi) {
            uint4 kf[8];
            {
                const int ko = my_lo * 4096;
                #pragma unroll
                for (int n = 0; n < 4; ++n)
                    #pragma unroll
                    for (int hf = 0; hf < 2; ++hf)
                        kf[n * 2 + hf] = *(const uint4*)(kp + ko + n * 1024 + hf * 32);
            }

            for (int kt = my_lo; kt < my_hi; ++kt) {
                uint4 vf[8];
                {
                    const int vo = kt * 64;
                    #pragma unroll
                    for (int dn = 0; dn < 4; ++dn)
                        #pragma unroll
                        for (int hf = 0; hf < 2; ++hf)
                            vf[dn * 2 + hf] = *(const uint4*)(vp + dn * 32768 + vo + hf * 32);
                }
                uint4 kn[8];
                if (kt + 1 < my_hi) {
                    const int ko = (kt + 1) * 4096;
                    #pragma unroll
                    for (int n = 0; n < 4; ++n)
                        #pragma unroll
                        for (int hf = 0; hf < 2; ++hf)
                            kn[n * 2 + hf] = *(const uint4*)(kp + ko + n * 1024 + hf * 32);
                }

                // S = Q K^T
                f32x4 s[2][4];
                #pragma unroll
                for (int n = 0; n < 4; ++n) {
                    bf16x8 b0 = as_bf8(kf[n * 2]);
                    bf16x8 b1 = as_bf8(kf[n * 2 + 1]);
                    #pragma unroll
                    for (int g = 0; g < 2; ++g) {
                        f32x4 zz = zero;
                        zz = __builtin_amdgcn_mfma_f32_16x16x32_bf16(qa[g][0], b0, zz, 0, 0, 0);
                        s[g][n] = __builtin_amdgcn_mfma_f32_16x16x32_bf16(qa[g][1], b1, zz, 0, 0, 0);
                    }
                }

                // p = exp2(S*c1 - slope2*|q-k|), truncate bf16, swizzled LDS store
                #pragma unroll
                for (int n = 0; n < 4; ++n) {
                    float kg = (float)(kt * 64 + n * 16 + ln);
                    int bswz = ((2 * n + (ln >> 3)) ^ quad) * 8 + (ln & 7);
                    #pragma unroll
                    for (int g = 0; g < 2; ++g) {
                        #pragma unroll
                        for (int r = 0; r < 4; ++r) {
                            float d = qrf[g][r] - kg;
                            float arg = fmaf(s[g][n][r], c1, -slope2 * fabsf(d));
                            float p = fexp2(arg);
                            Ps[w][g * 16 + quad * 4 + r][bswz] = (ushort)(fasu(p) >> 16);
                        }
                    }
                }
                // no barrier: Ps[w] is wave-private

                // O += P V ; lsum += P * ones
                #pragma unroll
                for (int hf = 0; hf < 2; ++hf) {
                    bf16x8 ap0 = as_bf8(*(const uint4*)&Ps[w][ln]     [((hf * 4 + quad) ^ (ln >> 2)) * 8]);
                    bf16x8 ap1 = as_bf8(*(const uint4*)&Ps[w][16 + ln][((hf * 4 + quad) ^ (ln >> 2)) * 8]);
                    #pragma unroll
                    for (int dn = 0; dn < 4; ++dn) {
                        bf16x8 bv = as_bf8(vf[dn * 2 + hf]);
                        o[0][dn] = __builtin_amdgcn_mfma_f32_16x16x32_bf16(ap0, bv, o[0][dn], 0, 0, 0);
                        o[1][dn] = __builtin_amdgcn_mfma_f32_16x16x32_bf16(ap1, bv, o[1][dn], 0, 0, 0);
                    }
                    lsum[0] = __builtin_amdgcn_mfma_f32_16x16x32_bf16(ap0, ones, lsum[0], 0, 0, 0);
                    lsum[1] = __builtin_amdgcn_mfma_f32_16x16x32_bf16(ap1, ones, lsum[1], 0, 0, 0);
                }

                #pragma unroll
                for (int i = 0; i < 8; ++i) kf[i] = kn[i];
            }
        }

        // -------- single-phase cross-wave merge --------
        __syncthreads();  // all loops done; Ps dead; Rbuf safe
        if (w > 0) {
            float* dst = &Rbuf[w - 1][lane][0];
            #pragma unroll
            for (int g = 0; g < 2; ++g) {
                #pragma unroll
                for (int dn = 0; dn < 4; ++dn)
                    #pragma unroll
                    for (int r = 0; r < 4; ++r)
                        dst[g * 16 + dn * 4 + r] = o[g][dn][r];
                #pragma unroll
                for (int r = 0; r < 4; ++r)
                    dst[32 + g * 4 + r] = lsum[g][r];
            }
        }
        __syncthreads();
        if (w == 0) {
            #pragma unroll
            for (int j = 0; j < 3; ++j) {
                const float* src = &Rbuf[j][lane][0];
                #pragma unroll
                for (int g = 0; g < 2; ++g) {
                    #pragma unroll
                    for (int dn = 0; dn < 4; ++dn)
                        #pragma unroll
                        for (int r = 0; r < 4; ++r)
                            o[g][dn][r] += src[g * 16 + dn * 4 + r];
                    #pragma unroll
                    for (int r = 0; r < 4; ++r)
                        lsum[g][r] += src[32 + g * 4 + r];
                }
            }
            // normalize, write [B][T][D] bf16
            #pragma unroll
            for (int g = 0; g < 2; ++g) {
                #pragma unroll
                for (int r = 0; r < 4; ++r) {
                    float inv = __builtin_amdgcn_rcpf(lsum[g][r]);
                    int q = qbase + g * 16 + quad * 4 + r;
                    size_t ob = ((size_t)(b * TT + q)) * DD + h * HD;
                    #pragma unroll
                    for (int dn = 0; dn < 4; ++dn)
                        outp[ob + dn * 16 + ln] = f2bf(o[g][dn][r] * inv);
                }
            }
        }
    }
}

extern "C" void kernel_launch(void* const* d_in, const int* in_sizes, int n_in,
                              void* d_out, int out_size, void* d_ws, size_t ws_size,
                              hipStream_t stream) {
    const float* query = (const float*)d_in[0];
    const float* key   = (const float*)d_in[1];
    const float* value = (const float*)d_in[2];
    const float* Wq = (const float*)d_in[3];
    const float* bq = (const float*)d_in[4];
    const float* Wk = (const float*)d_in[5];
    const float* bk = (const float*)d_in[6];
    const float* Wv = (const float*)d_in[7];
    const float* bv = (const float*)d_in[8];
    const float* Wo = (const float*)d_in[9];
    const float* bo = (const float*)d_in[10];
    float* out = (float*)d_out;

    char* ws = (char*)d_ws;
    const size_t MB = 1024 * 1024;
    ushort* Xq  = (ushort*)(ws + 0);
    ushort* Xk  = (ushort*)(ws + 8 * MB);
    ushort* Xv  = (ushort*)(ws + 16 * MB);
    ushort* Wtq = (ushort*)(ws + 24 * MB);
    ushort* Wtk = (ushort*)(ws + 26 * MB);
    ushort* Wtv = (ushort*)(ws + 28 * MB);
    ushort* Wto = (ushort*)(ws + 30 * MB);
    ushort* Qh  = (ushort*)(ws + 32 * MB);
    ushort* Kh  = (ushort*)(ws + 40 * MB);
    ushort* Vh  = (ushort*)(ws + 48 * MB);
    ushort* Vt   = (ushort*)(ws + 16 * MB);  // reuse Xv (free after QKV gemm)
    ushort* attn = (ushort*)(ws + 0);        // reuse Xq (free after QKV gemm)

    // conversions + weight transpose, one launch
    prep<<<dim3(4096, 4), 256, 0, stream>>>(query, key, value, Wq, Wk, Wv, Wo,
                                            Xq, Xk, Xv, Wtq, Wtk, Wtv, Wto);

    // QKV projections: one z-batched launch, 768 blocks
    gemm_mfma<128, 0><<<dim3(8, 32, 3), 256, 0, stream>>>(
        Xq, Wtq, bq, Qh,  Xk, Wtk, bk, Kh,  Xv, Wtv, bv, Vh);

    vtrans<<<dim3(TT / 64, BSZ * HH), 256, 0, stream>>>(Vh, Vt);

    // persistent: 1024 blocks, 2 folded items each
    attn_kernel<<<dim3(1024), 256, 0, stream>>>(Qh, Kh, Vt, attn);

    // output projection: 64x128 tiles, 512 blocks
    gemm_mfma<64, 1><<<dim3(8, 64, 1), 256, 0, stream>>>(
        attn, Wto, bo, out,  attn, Wto, bo, out,  attn, Wto, bo, out);
}

// Round 7
// 255.216 us; speedup vs baseline: 1.4489x; 1.4489x over previous
//
#include <hip/hip_runtime.h>
#include <stdint.h>

#define BSZ 2
#define TT 2048
#define DD 1024
#define HH 16
#define HD 64

typedef __bf16 bf16x8 __attribute__((ext_vector_type(8)));
typedef float f32x4 __attribute__((ext_vector_type(4)));

// fast exp2: single v_exp_f32 (builtin if available, else inline asm + hazard nop)
#if __has_builtin(__builtin_amdgcn_exp2f)
__device__ __forceinline__ float fexp2(float x) { return __builtin_amdgcn_exp2f(x); }
#else
__device__ __forceinline__ float fexp2(float x) {
    float r; asm("v_exp_f32 %0, %1\n\ts_nop 1" : "=v"(r) : "v"(x)); return r;
}
#endif

__device__ __forceinline__ unsigned short f2bf(float f) {
    union { float f; unsigned u; } c; c.f = f;
    unsigned u = c.u;
    unsigned r = u + 0x7fffu + ((u >> 16) & 1u);
    return (unsigned short)(r >> 16);
}
__device__ __forceinline__ unsigned fasu(float f) {
    union { float f; unsigned u; } c; c.f = f; return c.u;
}

union U4BF { uint4 u; bf16x8 b; };
__device__ __forceinline__ bf16x8 as_bf8(uint4 v) { U4BF c; c.u = v; return c.b; }

// ---- async global->LDS, 16B per lane; LDS dst = wave-uniform base + lane*16 ----
#if __has_builtin(__builtin_amdgcn_global_load_lds)
__device__ __forceinline__ void gl_lds16(const ushort* g, ushort* l) {
    __builtin_amdgcn_global_load_lds(
        (const __attribute__((address_space(1))) uint32_t*)g,
        (__attribute__((address_space(3))) uint32_t*)l, 16, 0, 0);
}
#define GLL_LANE 1
#else
__device__ __forceinline__ void gl_lds16_fallback(const ushort* g, ushort* l, int lane) {
    *(uint4*)(l + lane * 8) = *(const uint4*)(g);
}
#define GLL_LANE 0
#endif

// ---------------- prep: y<3 -> fp32->bf16 cvt of q/k/v ; y==3 -> W transpose ----
__global__ __launch_bounds__(256)
void prep(const float* __restrict__ q, const float* __restrict__ k,
          const float* __restrict__ v,
          const float* __restrict__ W0, const float* __restrict__ W1,
          const float* __restrict__ W2, const float* __restrict__ W3,
          ushort* __restrict__ xq, ushort* __restrict__ xk, ushort* __restrict__ xv,
          ushort* __restrict__ T0, ushort* __restrict__ T1,
          ushort* __restrict__ T2, ushort* __restrict__ T3) {
    __shared__ float sh[32][33];
    const int y = blockIdx.y;
    if (y < 3) {
        const float* in = (y == 0) ? q : (y == 1) ? k : v;
        ushort* out = (y == 0) ? xq : (y == 1) ? xk : xv;
        int i = blockIdx.x * 256 + threadIdx.x;
        float4 val = ((const float4*)in)[i];
        ushort4 o;
        o.x = f2bf(val.x); o.y = f2bf(val.y); o.z = f2bf(val.z); o.w = f2bf(val.w);
        ((ushort4*)out)[i] = o;
    } else {
        const int x = blockIdx.x;
        const float* src; ushort* dst;
        switch (x >> 10) {
            case 0:  src = W0; dst = T0; break;
            case 1:  src = W1; dst = T1; break;
            case 2:  src = W2; dst = T2; break;
            default: src = W3; dst = T3; break;
        }
        const int tile = x & 1023;
        const int k0 = (tile >> 5) * 32, n0 = (tile & 31) * 32;
        const int tx = threadIdx.x & 31, ty = threadIdx.x >> 5;  // ty 0..7
        #pragma unroll
        for (int p = 0; p < 4; ++p)
            sh[ty + 8 * p][tx] = src[(size_t)(k0 + ty + 8 * p) * DD + n0 + tx];
        __syncthreads();
        #pragma unroll
        for (int p = 0; p < 4; ++p)
            dst[(size_t)(n0 + ty + 8 * p) * DD + k0 + tx] = f2bf(sh[tx][ty + 8 * p]);
    }
}

// ---------------- V transpose: Vt[bh][d][t] = Vh[bh][t][d] ----------------
__global__ __launch_bounds__(256)
void vtrans(const ushort* __restrict__ Vh, ushort* __restrict__ Vt) {
    __shared__ ushort sh[64][72];
    const int tid = threadIdx.x;
    const int bh = blockIdx.y;
    const int t0 = blockIdx.x * 64;
    const size_t base = (size_t)bh * (TT * HD);
    #pragma unroll
    for (int it = 0; it < 2; ++it) {
        int u = tid + it * 256;
        int r = u >> 3, c8 = (u & 7) * 8;
        *(uint4*)&sh[r][c8] = *(const uint4*)(Vh + base + (size_t)(t0 + r) * HD + c8);
    }
    __syncthreads();
    #pragma unroll
    for (int it = 0; it < 2; ++it) {
        int u = tid + it * 256;
        int d = u >> 3, c8 = (u & 7) * 8;
        alignas(16) ushort tmp[8];
        #pragma unroll
        for (int p = 0; p < 8; ++p) tmp[p] = sh[c8 + p][d];
        *(uint4*)(Vt + base + (size_t)d * TT + t0 + c8) = *(const uint4*)tmp;
    }
}

// ---------------- BMx128 bf16 MFMA GEMM with global_load_lds staging ----------------
// OUT_MODE 0: z-batched QKV, bf16 out [bh][t][d]. OUT_MODE 1: fp32 out [4096][1024].
template<int BM, int OUT_MODE>
__global__ __launch_bounds__(256)
void gemm_mfma(const ushort* __restrict__ A0, const ushort* __restrict__ B0,
               const float* __restrict__ c0, void* __restrict__ d0,
               const ushort* __restrict__ A1, const ushort* __restrict__ B1,
               const float* __restrict__ c1, void* __restrict__ d1,
               const ushort* __restrict__ A2, const ushort* __restrict__ B2,
               const float* __restrict__ c2, void* __restrict__ d2) {
    constexpr int TI = 4;
    constexpr int TJ = (BM == 128) ? 4 : 2;
    constexpr int WC = (BM == 128) ? 2 : 4;
    __shared__ __attribute__((aligned(16))) ushort As[BM][32];
    __shared__ __attribute__((aligned(16))) ushort Bs[128][32];
    const ushort* A; const ushort* Bt; const float* bias; void* outp;
    switch (blockIdx.z) {
        case 0:  A = A0; Bt = B0; bias = c0; outp = d0; break;
        case 1:  A = A1; Bt = B1; bias = c1; outp = d1; break;
        default: A = A2; Bt = B2; bias = c2; outp = d2; break;
    }
    const int tid  = threadIdx.x;
    const int lane = tid & 63, w = tid >> 6;
    const int wr = w / WC, wc = w % WC;
    const int ln = lane & 15, quad = lane >> 4;
    const int m0 = blockIdx.y * BM, n0 = blockIdx.x * 128;

    const f32x4 zero = {0.f, 0.f, 0.f, 0.f};
    f32x4 acc[TI][TJ];
    #pragma unroll
    for (int i = 0; i < TI; ++i)
        #pragma unroll
        for (int j = 0; j < TJ; ++j) acc[i][j] = zero;

    const int lr  = lane >> 2;        // row within 16-row stripe
    const int lc8 = (lane & 3) * 8;   // 0,8,16,24

    for (int kb = 0; kb < 1024; kb += 32) {
        #pragma unroll
        for (int it = 0; it < BM / 64; ++it) {
            int r0 = it * 64 + w * 16;
#if GLL_LANE
            gl_lds16(A + (size_t)(m0 + r0 + lr) * 1024 + kb + lc8, &As[r0][0]);
#else
            gl_lds16_fallback(A + (size_t)(m0 + r0 + lr) * 1024 + kb + lc8, &As[r0][0], lane);
#endif
        }
        #pragma unroll
        for (int it = 0; it < 2; ++it) {
            int r0 = it * 64 + w * 16;
#if GLL_LANE
            gl_lds16(Bt + (size_t)(n0 + r0 + lr) * 1024 + kb + lc8, &Bs[r0][0]);
#else
            gl_lds16_fallback(Bt + (size_t)(n0 + r0 + lr) * 1024 + kb + lc8, &Bs[r0][0], lane);
#endif
        }
        __syncthreads();
        bf16x8 af[TI], bfr[TJ];
        #pragma unroll
        for (int i = 0; i < TI; ++i)
            af[i] = as_bf8(*(const uint4*)&As[wr * 64 + i * 16 + ln][quad * 8]);
        #pragma unroll
        for (int j = 0; j < TJ; ++j)
            bfr[j] = as_bf8(*(const uint4*)&Bs[wc * (TJ * 16) + j * 16 + ln][quad * 8]);
        #pragma unroll
        for (int i = 0; i < TI; ++i)
            #pragma unroll
            for (int j = 0; j < TJ; ++j)
                acc[i][j] = __builtin_amdgcn_mfma_f32_16x16x32_bf16(af[i], bfr[j], acc[i][j], 0, 0, 0);
        __syncthreads();
    }

    #pragma unroll
    for (int j = 0; j < TJ; ++j) {
        int n = n0 + wc * (TJ * 16) + j * 16 + ln;
        float bv = bias[n];
        #pragma unroll
        for (int i = 0; i < TI; ++i) {
            #pragma unroll
            for (int r = 0; r < 4; ++r) {
                int m = m0 + wr * 64 + i * 16 + quad * 4 + r;
                float v = acc[i][j][r] + bv;
                if (OUT_MODE == 0) {
                    int b = m >> 11, t = m & 2047, h = n >> 6, d = n & 63;
                    ((ushort*)outp)[(((size_t)(b * HH + h)) * TT + t) * HD + d] = f2bf(v);
                } else {
                    ((float*)outp)[(size_t)m * 1024 + n] = v;
                }
            }
        }
    }
}

// ---------------- flash attention: persistent folded, single-phase merge ----------
// 1024 blocks; block p runs items p and 2047-p (heavy-first sorted).
// Item = (b,h,32 q-rows); 4 waves k-split; one-shot LDS merge.
// Qh,Kh: [bh][t][d]   Vtg: [bh][d][t]   out: [B][T][D] bf16
__global__ __launch_bounds__(256)
void attn_kernel(const ushort* __restrict__ Qh, const ushort* __restrict__ Kh,
                 const ushort* __restrict__ Vtg, ushort* __restrict__ outp) {
    // Ps: ushort[4][32][72]=18432B ; Rbuf: float[3][64][44]=33792B (overlaid)
    __shared__ __attribute__((aligned(16))) char smem[33792];
    ushort (*Ps)[32][72] = (ushort (*)[32][72])smem;
    float  (*Rbuf)[64][44] = (float (*)[64][44])smem;

    const int tid  = threadIdx.x;
    const int lane = tid & 63, w = tid >> 6;     // w = k-chunk index 0..3
    const int ln = lane & 15, quad = lane >> 4;

    bf16x8 ones;
    {
        union { ushort us[8]; bf16x8 v; } uu;
        #pragma unroll
        for (int p = 0; p < 8; ++p) uu.us[p] = 0x3F80;
        ones = uu.v;
    }
    const f32x4 zero = {0.f, 0.f, 0.f, 0.f};
    const float c1 = 0.125f * 1.44269504f;  // scale*log2e

    for (int sel = 0; sel < 2; ++sel) {
        __syncthreads();  // Rbuf reads (prev item) done before Ps reuse
        const int item = sel ? (2047 - (int)blockIdx.x) : (int)blockIdx.x;
        const int h = 15 - (item >> 7);
        const int rr = item & 127;
        const int b = rr & 1;
        const int qt = rr >> 1;
        const int bh = b * 16 + h;
        const int qbase = qt * 32;
        const float slope2 = exp2f(-0.5f * (float)(h + 1)) * 1.44269504f;
        const size_t base = (size_t)bh * (TT * HD);

        // ALiBi band: tiles with slope2*dist >= 18 contribute < ~2^-11 of mass
        const int D = (int)ceilf(18.0f / slope2);
        int lo = qbase - D;
        int kt_lo = (lo > 0) ? (lo >> 6) : 0;
        int kt_hi = (qbase + 32 + D + 63) >> 6;
        if (kt_hi > TT / 64) kt_hi = TT / 64;
        const int nt = kt_hi - kt_lo;
        const int cs = (nt + 3) >> 2;
        const int my_lo = kt_lo + w * cs;
        const int my_hi = (my_lo + cs < kt_hi) ? (my_lo + cs) : kt_hi;

        // Q fragments (A-layout)
        bf16x8 qa[2][2];
        #pragma unroll
        for (int g = 0; g < 2; ++g) {
            const uint4* qp = (const uint4*)(Qh + base + (size_t)(qbase + g * 16 + ln) * HD);
            qa[g][0] = as_bf8(qp[quad]);
            qa[g][1] = as_bf8(qp[4 + quad]);
        }
        f32x4 o[2][4], lsum[2];
        #pragma unroll
        for (int g = 0; g < 2; ++g) {
            lsum[g] = zero;
            #pragma unroll
            for (int dn = 0; dn < 4; ++dn) o[g][dn] = zero;
        }
        float qrf[2][4];
        #pragma unroll
        for (int g = 0; g < 2; ++g)
            #pragma unroll
            for (int r = 0; r < 4; ++r)
                qrf[g][r] = (float)(qbase + g * 16 + quad * 4 + r);

        const ushort* kp = Kh  + base + (size_t)ln * HD + quad * 8;
        const ushort* vp = Vtg + base + (size_t)ln * TT + quad * 8;

        if (my_lo < my_hi) {
            uint4 kf[8];
            {
                const int ko = my_lo * 4096;
                #pragma unroll
                for (int n = 0; n < 4; ++n)
                    #pragma unroll
                    for (int hf = 0; hf < 2; ++hf)
                        kf[n * 2 + hf] = *(const uint4*)(kp + ko + n * 1024 + hf * 32);
            }

            for (int kt = my_lo; kt < my_hi; ++kt) {
                uint4 vf[8];
                {
                    const int vo = kt * 64;
                    #pragma unroll
                    for (int dn = 0; dn < 4; ++dn)
                        #pragma unroll
                        for (int hf = 0; hf < 2; ++hf)
                            vf[dn * 2 + hf] = *(const uint4*)(vp + dn * 32768 + vo + hf * 32);
                }
                uint4 kn[8];
                if (kt + 1 < my_hi) {
                    const int ko = (kt + 1) * 4096;
                    #pragma unroll
                    for (int n = 0; n < 4; ++n)
                        #pragma unroll
                        for (int hf = 0; hf < 2; ++hf)
                            kn[n * 2 + hf] = *(const uint4*)(kp + ko + n * 1024 + hf * 32);
                }

                // S = Q K^T
                f32x4 s[2][4];
                #pragma unroll
                for (int n = 0; n < 4; ++n) {
                    bf16x8 b0 = as_bf8(kf[n * 2]);
                    bf16x8 b1 = as_bf8(kf[n * 2 + 1]);
                    #pragma unroll
                    for (int g = 0; g < 2; ++g) {
                        f32x4 zz = zero;
                        zz = __builtin_amdgcn_mfma_f32_16x16x32_bf16(qa[g][0], b0, zz, 0, 0, 0);
                        s[g][n] = __builtin_amdgcn_mfma_f32_16x16x32_bf16(qa[g][1], b1, zz, 0, 0, 0);
                    }
                }

                // p = exp2(S*c1 - slope2*|q-k|), truncate bf16, swizzled LDS store
                #pragma unroll
                for (int n = 0; n < 4; ++n) {
                    float kg = (float)(kt * 64 + n * 16 + ln);
                    int bswz = ((2 * n + (ln >> 3)) ^ quad) * 8 + (ln & 7);
                    #pragma unroll
                    for (int g = 0; g < 2; ++g) {
                        #pragma unroll
                        for (int r = 0; r < 4; ++r) {
                            float d = qrf[g][r] - kg;
                            float arg = fmaf(s[g][n][r], c1, -slope2 * fabsf(d));
                            float p = fexp2(arg);
                            Ps[w][g * 16 + quad * 4 + r][bswz] = (ushort)(fasu(p) >> 16);
                        }
                    }
                }
                // no barrier: Ps[w] is wave-private

                // O += P V ; lsum += P * ones
                #pragma unroll
                for (int hf = 0; hf < 2; ++hf) {
                    bf16x8 ap0 = as_bf8(*(const uint4*)&Ps[w][ln]     [((hf * 4 + quad) ^ (ln >> 2)) * 8]);
                    bf16x8 ap1 = as_bf8(*(const uint4*)&Ps[w][16 + ln][((hf * 4 + quad) ^ (ln >> 2)) * 8]);
                    #pragma unroll
                    for (int dn = 0; dn < 4; ++dn) {
                        bf16x8 bv = as_bf8(vf[dn * 2 + hf]);
                        o[0][dn] = __builtin_amdgcn_mfma_f32_16x16x32_bf16(ap0, bv, o[0][dn], 0, 0, 0);
                        o[1][dn] = __builtin_amdgcn_mfma_f32_16x16x32_bf16(ap1, bv, o[1][dn], 0, 0, 0);
                    }
                    lsum[0] = __builtin_amdgcn_mfma_f32_16x16x32_bf16(ap0, ones, lsum[0], 0, 0, 0);
                    lsum[1] = __builtin_amdgcn_mfma_f32_16x16x32_bf16(ap1, ones, lsum[1], 0, 0, 0);
                }

                #pragma unroll
                for (int i = 0; i < 8; ++i) kf[i] = kn[i];
            }
        }

        // -------- single-phase cross-wave merge --------
        __syncthreads();  // all loops done; Ps dead; Rbuf safe
        if (w > 0) {
            float* dst = &Rbuf[w - 1][lane][0];
            #pragma unroll
            for (int g = 0; g < 2; ++g) {
                #pragma unroll
                for (int dn = 0; dn < 4; ++dn)
                    #pragma unroll
                    for (int r = 0; r < 4; ++r)
                        dst[g * 16 + dn * 4 + r] = o[g][dn][r];
                #pragma unroll
                for (int r = 0; r < 4; ++r)
                    dst[32 + g * 4 + r] = lsum[g][r];
            }
        }
        __syncthreads();
        if (w == 0) {
            #pragma unroll
            for (int j = 0; j < 3; ++j) {
                const float* src = &Rbuf[j][lane][0];
                #pragma unroll
                for (int g = 0; g < 2; ++g) {
                    #pragma unroll
                    for (int dn = 0; dn < 4; ++dn)
                        #pragma unroll
                        for (int r = 0; r < 4; ++r)
                            o[g][dn][r] += src[g * 16 + dn * 4 + r];
                    #pragma unroll
                    for (int r = 0; r < 4; ++r)
                        lsum[g][r] += src[32 + g * 4 + r];
                }
            }
            // normalize, write [B][T][D] bf16
            #pragma unroll
            for (int g = 0; g < 2; ++g) {
                #pragma unroll
                for (int r = 0; r < 4; ++r) {
                    float inv = __builtin_amdgcn_rcpf(lsum[g][r]);
                    int q = qbase + g * 16 + quad * 4 + r;
                    size_t ob = ((size_t)(b * TT + q)) * DD + h * HD;
                    #pragma unroll
                    for (int dn = 0; dn < 4; ++dn)
                        outp[ob + dn * 16 + ln] = f2bf(o[g][dn][r] * inv);
                }
            }
        }
    }
}

extern "C" void kernel_launch(void* const* d_in, const int* in_sizes, int n_in,
                              void* d_out, int out_size, void* d_ws, size_t ws_size,
                              hipStream_t stream) {
    const float* query = (const float*)d_in[0];
    const float* key   = (const float*)d_in[1];
    const float* value = (const float*)d_in[2];
    const float* Wq = (const float*)d_in[3];
    const float* bq = (const float*)d_in[4];
    const float* Wk = (const float*)d_in[5];
    const float* bk = (const float*)d_in[6];
    const float* Wv = (const float*)d_in[7];
    const float* bv = (const float*)d_in[8];
    const float* Wo = (const float*)d_in[9];
    const float* bo = (const float*)d_in[10];
    float* out = (float*)d_out;

    char* ws = (char*)d_ws;
    const size_t MB = 1024 * 1024;
    ushort* Xq  = (ushort*)(ws + 0);
    ushort* Xk  = (ushort*)(ws + 8 * MB);
    ushort* Xv  = (ushort*)(ws + 16 * MB);
    ushort* Wtq = (ushort*)(ws + 24 * MB);
    ushort* Wtk = (ushort*)(ws + 26 * MB);
    ushort* Wtv = (ushort*)(ws + 28 * MB);
    ushort* Wto = (ushort*)(ws + 30 * MB);
    ushort* Qh  = (ushort*)(ws + 32 * MB);
    ushort* Kh  = (ushort*)(ws + 40 * MB);
    ushort* Vh  = (ushort*)(ws + 48 * MB);
    ushort* Vt   = (ushort*)(ws + 16 * MB);  // reuse Xv (free after QKV gemm)
    ushort* attn = (ushort*)(ws + 0);        // reuse Xq (free after QKV gemm)

    // conversions + weight transpose, one launch
    prep<<<dim3(4096, 4), 256, 0, stream>>>(query, key, value, Wq, Wk, Wv, Wo,
                                            Xq, Xk, Xv, Wtq, Wtk, Wtv, Wto);

    // QKV projections: one z-batched launch, 768 blocks
    gemm_mfma<128, 0><<<dim3(8, 32, 3), 256, 0, stream>>>(
        Xq, Wtq, bq, Qh,  Xk, Wtk, bk, Kh,  Xv, Wtv, bv, Vh);

    vtrans<<<dim3(TT / 64, BSZ * HH), 256, 0, stream>>>(Vh, Vt);

    // persistent: 1024 blocks, 2 folded items each
    attn_kernel<<<dim3(1024), 256, 0, stream>>>(Qh, Kh, Vt, attn);

    // output projection: 64x128 tiles, 512 blocks
    gemm_mfma<64, 1><<<dim3(8, 64, 1), 256, 0, stream>>>(
        attn, Wto, bo, out,  attn, Wto, bo, out,  attn, Wto, bo, out);
}

// Round 8
// 243.018 us; speedup vs baseline: 1.5216x; 1.0502x over previous
//
#include <hip/hip_runtime.h>
#include <stdint.h>

#define BSZ 2
#define TT 2048
#define DD 1024
#define HH 16
#define HD 64

typedef __bf16 bf16x8 __attribute__((ext_vector_type(8)));
typedef float f32x4 __attribute__((ext_vector_type(4)));

// fast exp2: single v_exp_f32 (builtin if available, else inline asm + hazard nop)
#if __has_builtin(__builtin_amdgcn_exp2f)
__device__ __forceinline__ float fexp2(float x) { return __builtin_amdgcn_exp2f(x); }
#else
__device__ __forceinline__ float fexp2(float x) {
    float r; asm("v_exp_f32 %0, %1\n\ts_nop 1" : "=v"(r) : "v"(x)); return r;
}
#endif

__device__ __forceinline__ unsigned short f2bf(float f) {
    union { float f; unsigned u; } c; c.f = f;
    unsigned u = c.u;
    unsigned r = u + 0x7fffu + ((u >> 16) & 1u);
    return (unsigned short)(r >> 16);
}
__device__ __forceinline__ unsigned fasu(float f) {
    union { float f; unsigned u; } c; c.f = f; return c.u;
}

union U4BF { uint4 u; bf16x8 b; };
__device__ __forceinline__ bf16x8 as_bf8(uint4 v) { U4BF c; c.u = v; return c.b; }

// ---- async global->LDS, 16B per lane; LDS dst = wave-uniform base + lane*16 ----
#if __has_builtin(__builtin_amdgcn_global_load_lds)
__device__ __forceinline__ void gl_lds16(const ushort* g, ushort* l) {
    __builtin_amdgcn_global_load_lds(
        (const __attribute__((address_space(1))) uint32_t*)g,
        (__attribute__((address_space(3))) uint32_t*)l, 16, 0, 0);
}
#define GLL_LANE 1
#else
__device__ __forceinline__ void gl_lds16_fallback(const ushort* g, ushort* l, int lane) {
    *(uint4*)(l + lane * 8) = *(const uint4*)(g);
}
#define GLL_LANE 0
#endif

// ---------------- prep: y<3 -> fp32->bf16 cvt of q/k/v ; y==3 -> W transpose ----
__global__ __launch_bounds__(256)
void prep(const float* __restrict__ q, const float* __restrict__ k,
          const float* __restrict__ v,
          const float* __restrict__ W0, const float* __restrict__ W1,
          const float* __restrict__ W2, const float* __restrict__ W3,
          ushort* __restrict__ xq, ushort* __restrict__ xk, ushort* __restrict__ xv,
          ushort* __restrict__ T0, ushort* __restrict__ T1,
          ushort* __restrict__ T2, ushort* __restrict__ T3,
          int* __restrict__ ctr) {
    __shared__ float sh[32][33];
    const int y = blockIdx.y;
    if (y < 3) {
        const float* in = (y == 0) ? q : (y == 1) ? k : v;
        ushort* out = (y == 0) ? xq : (y == 1) ? xk : xv;
        int i = blockIdx.x * 256 + threadIdx.x;
        float4 val = ((const float4*)in)[i];
        ushort4 o;
        o.x = f2bf(val.x); o.y = f2bf(val.y); o.z = f2bf(val.z); o.w = f2bf(val.w);
        ((ushort4*)out)[i] = o;
    } else {
        if (blockIdx.x == 0 && threadIdx.x == 0) *ctr = 1024;  // attn work counter
        const int x = blockIdx.x;
        const float* src; ushort* dst;
        switch (x >> 10) {
            case 0:  src = W0; dst = T0; break;
            case 1:  src = W1; dst = T1; break;
            case 2:  src = W2; dst = T2; break;
            default: src = W3; dst = T3; break;
        }
        const int tile = x & 1023;
        const int k0 = (tile >> 5) * 32, n0 = (tile & 31) * 32;
        const int tx = threadIdx.x & 31, ty = threadIdx.x >> 5;  // ty 0..7
        #pragma unroll
        for (int p = 0; p < 4; ++p)
            sh[ty + 8 * p][tx] = src[(size_t)(k0 + ty + 8 * p) * DD + n0 + tx];
        __syncthreads();
        #pragma unroll
        for (int p = 0; p < 4; ++p)
            dst[(size_t)(n0 + ty + 8 * p) * DD + k0 + tx] = f2bf(sh[tx][ty + 8 * p]);
    }
}

// ---------------- BMx128 bf16 MFMA GEMM with global_load_lds staging ----------------
// OUT_MODE 0: z-batched QKV. z<2 -> bf16 [bh][t][d]; z==2 -> bf16 Vt [bh][d][t].
// OUT_MODE 1: fp32 out row-major [4096][1024].
template<int BM, int OUT_MODE>
__global__ __launch_bounds__(256)
void gemm_mfma(const ushort* __restrict__ A0, const ushort* __restrict__ B0,
               const float* __restrict__ c0, void* __restrict__ d0,
               const ushort* __restrict__ A1, const ushort* __restrict__ B1,
               const float* __restrict__ c1, void* __restrict__ d1,
               const ushort* __restrict__ A2, const ushort* __restrict__ B2,
               const float* __restrict__ c2, void* __restrict__ d2) {
    constexpr int TI = 4;
    constexpr int TJ = (BM == 128) ? 4 : 2;
    constexpr int WC = (BM == 128) ? 2 : 4;
    __shared__ __attribute__((aligned(16))) ushort As[BM][32];
    __shared__ __attribute__((aligned(16))) ushort Bs[128][32];
    const ushort* A; const ushort* Bt; const float* bias; void* outp;
    const int z = blockIdx.z;
    switch (z) {
        case 0:  A = A0; Bt = B0; bias = c0; outp = d0; break;
        case 1:  A = A1; Bt = B1; bias = c1; outp = d1; break;
        default: A = A2; Bt = B2; bias = c2; outp = d2; break;
    }
    const int tid  = threadIdx.x;
    const int lane = tid & 63, w = tid >> 6;
    const int wr = w / WC, wc = w % WC;
    const int ln = lane & 15, quad = lane >> 4;
    const int m0 = blockIdx.y * BM, n0 = blockIdx.x * 128;

    const f32x4 zero = {0.f, 0.f, 0.f, 0.f};
    f32x4 acc[TI][TJ];
    #pragma unroll
    for (int i = 0; i < TI; ++i)
        #pragma unroll
        for (int j = 0; j < TJ; ++j) acc[i][j] = zero;

    const int lr  = lane >> 2;        // row within 16-row stripe
    const int lc8 = (lane & 3) * 8;   // 0,8,16,24

    for (int kb = 0; kb < 1024; kb += 32) {
        #pragma unroll
        for (int it = 0; it < BM / 64; ++it) {
            int r0 = it * 64 + w * 16;
#if GLL_LANE
            gl_lds16(A + (size_t)(m0 + r0 + lr) * 1024 + kb + lc8, &As[r0][0]);
#else
            gl_lds16_fallback(A + (size_t)(m0 + r0 + lr) * 1024 + kb + lc8, &As[r0][0], lane);
#endif
        }
        #pragma unroll
        for (int it = 0; it < 2; ++it) {
            int r0 = it * 64 + w * 16;
#if GLL_LANE
            gl_lds16(Bt + (size_t)(n0 + r0 + lr) * 1024 + kb + lc8, &Bs[r0][0]);
#else
            gl_lds16_fallback(Bt + (size_t)(n0 + r0 + lr) * 1024 + kb + lc8, &Bs[r0][0], lane);
#endif
        }
        __syncthreads();
        bf16x8 af[TI], bfr[TJ];
        #pragma unroll
        for (int i = 0; i < TI; ++i)
            af[i] = as_bf8(*(const uint4*)&As[wr * 64 + i * 16 + ln][quad * 8]);
        #pragma unroll
        for (int j = 0; j < TJ; ++j)
            bfr[j] = as_bf8(*(const uint4*)&Bs[wc * (TJ * 16) + j * 16 + ln][quad * 8]);
        #pragma unroll
        for (int i = 0; i < TI; ++i)
            #pragma unroll
            for (int j = 0; j < TJ; ++j)
                acc[i][j] = __builtin_amdgcn_mfma_f32_16x16x32_bf16(af[i], bfr[j], acc[i][j], 0, 0, 0);
        __syncthreads();
    }

    #pragma unroll
    for (int j = 0; j < TJ; ++j) {
        int n = n0 + wc * (TJ * 16) + j * 16 + ln;
        float bv = bias[n];
        #pragma unroll
        for (int i = 0; i < TI; ++i) {
            int mb = m0 + wr * 64 + i * 16 + quad * 4;
            if (OUT_MODE == 0 && z == 2) {
                // V: write transposed Vt[bh][d][t], t = mb..mb+3 contiguous
                int b = mb >> 11, t = mb & 2047, h = n >> 6, d = n & 63;
                ushort4 pk;
                pk.x = f2bf(acc[i][j][0] + bv);
                pk.y = f2bf(acc[i][j][1] + bv);
                pk.z = f2bf(acc[i][j][2] + bv);
                pk.w = f2bf(acc[i][j][3] + bv);
                *(ushort4*)((ushort*)outp + ((size_t)((b * HH + h) * HD + d)) * TT + t) = pk;
            } else {
                #pragma unroll
                for (int r = 0; r < 4; ++r) {
                    int m = mb + r;
                    float v = acc[i][j][r] + bv;
                    if (OUT_MODE == 0) {
                        int b = m >> 11, t = m & 2047, h = n >> 6, d = n & 63;
                        ((ushort*)outp)[(((size_t)(b * HH + h)) * TT + t) * HD + d] = f2bf(v);
                    } else {
                        ((float*)outp)[(size_t)m * 1024 + n] = v;
                    }
                }
            }
        }
    }
}

// ---------------- flash attention: dynamic LPT schedule, banded ALiBi --------------
// 1024 blocks; first item = blockIdx.x (heaviest 1024), then atomic work stealing.
// Item = (b,h,32 q-rows); 4 waves k-split; one-shot LDS merge.
// Qh,Kh: [bh][t][d]   Vtg: [bh][d][t]   out: [B][T][D] bf16
__global__ __launch_bounds__(256)
void attn_kernel(const ushort* __restrict__ Qh, const ushort* __restrict__ Kh,
                 const ushort* __restrict__ Vtg, ushort* __restrict__ outp,
                 int* __restrict__ ctr) {
    // Ps: ushort[4][32][72]=18432B ; Rbuf: float[3][64][44]=33792B (overlaid)
    __shared__ __attribute__((aligned(16))) char smem[33792];
    __shared__ int s_item;
    ushort (*Ps)[32][72] = (ushort (*)[32][72])smem;
    float  (*Rbuf)[64][44] = (float (*)[64][44])smem;

    const int tid  = threadIdx.x;
    const int lane = tid & 63, w = tid >> 6;     // w = k-chunk index 0..3
    const int ln = lane & 15, quad = lane >> 4;

    bf16x8 ones;
    {
        union { ushort us[8]; bf16x8 v; } uu;
        #pragma unroll
        for (int p = 0; p < 8; ++p) uu.us[p] = 0x3F80;
        ones = uu.v;
    }
    const f32x4 zero = {0.f, 0.f, 0.f, 0.f};
    const float c1 = 0.125f * 1.44269504f;  // scale*log2e

    int item = blockIdx.x;  // heaviest 1024 items statically seeded
    while (item < 2048) {
        const int h = 15 - (item >> 7);      // heavy-first order
        const int rr = item & 127;
        const int b = rr & 1;
        const int qt = rr >> 1;
        const int bh = b * 16 + h;
        const int qbase = qt * 32;
        const float slope2 = exp2f(-0.5f * (float)(h + 1)) * 1.44269504f;
        const size_t base = (size_t)bh * (TT * HD);

        // ALiBi band: tiles with slope2*dist >= 18 contribute < ~2^-11 of mass
        const int D = (int)ceilf(18.0f / slope2);
        int lo = qbase - D;
        int kt_lo = (lo > 0) ? (lo >> 6) : 0;
        int kt_hi = (qbase + 32 + D + 63) >> 6;
        if (kt_hi > TT / 64) kt_hi = TT / 64;
        const int nt = kt_hi - kt_lo;
        const int cs = (nt + 3) >> 2;
        const int my_lo = kt_lo + w * cs;
        const int my_hi = (my_lo + cs < kt_hi) ? (my_lo + cs) : kt_hi;

        // Q fragments (A-layout)
        bf16x8 qa[2][2];
        #pragma unroll
        for (int g = 0; g < 2; ++g) {
            const uint4* qp = (const uint4*)(Qh + base + (size_t)(qbase + g * 16 + ln) * HD);
            qa[g][0] = as_bf8(qp[quad]);
            qa[g][1] = as_bf8(qp[4 + quad]);
        }
        f32x4 o[2][4], lsum[2];
        #pragma unroll
        for (int g = 0; g < 2; ++g) {
            lsum[g] = zero;
            #pragma unroll
            for (int dn = 0; dn < 4; ++dn) o[g][dn] = zero;
        }
        float qrf[2][4];
        #pragma unroll
        for (int g = 0; g < 2; ++g)
            #pragma unroll
            for (int r = 0; r < 4; ++r)
                qrf[g][r] = (float)(qbase + g * 16 + quad * 4 + r);

        const ushort* kp = Kh  + base + (size_t)ln * HD + quad * 8;
        const ushort* vp = Vtg + base + (size_t)ln * TT + quad * 8;

        if (my_lo < my_hi) {
            uint4 kf[8];
            {
                const int ko = my_lo * 4096;
                #pragma unroll
                for (int n = 0; n < 4; ++n)
                    #pragma unroll
                    for (int hf = 0; hf < 2; ++hf)
                        kf[n * 2 + hf] = *(const uint4*)(kp + ko + n * 1024 + hf * 32);
            }

            for (int kt = my_lo; kt < my_hi; ++kt) {
                uint4 vf[8];
                {
                    const int vo = kt * 64;
                    #pragma unroll
                    for (int dn = 0; dn < 4; ++dn)
                        #pragma unroll
                        for (int hf = 0; hf < 2; ++hf)
                            vf[dn * 2 + hf] = *(const uint4*)(vp + dn * 32768 + vo + hf * 32);
                }
                uint4 kn[8];
                if (kt + 1 < my_hi) {
                    const int ko = (kt + 1) * 4096;
                    #pragma unroll
                    for (int n = 0; n < 4; ++n)
                        #pragma unroll
                        for (int hf = 0; hf < 2; ++hf)
                            kn[n * 2 + hf] = *(const uint4*)(kp + ko + n * 1024 + hf * 32);
                }

                // S = Q K^T
                f32x4 s[2][4];
                #pragma unroll
                for (int n = 0; n < 4; ++n) {
                    bf16x8 b0 = as_bf8(kf[n * 2]);
                    bf16x8 b1 = as_bf8(kf[n * 2 + 1]);
                    #pragma unroll
                    for (int g = 0; g < 2; ++g) {
                        f32x4 zz = zero;
                        zz = __builtin_amdgcn_mfma_f32_16x16x32_bf16(qa[g][0], b0, zz, 0, 0, 0);
                        s[g][n] = __builtin_amdgcn_mfma_f32_16x16x32_bf16(qa[g][1], b1, zz, 0, 0, 0);
                    }
                }

                // p = exp2(S*c1 - slope2*|q-k|), truncate bf16, swizzled LDS store
                #pragma unroll
                for (int n = 0; n < 4; ++n) {
                    float kg = (float)(kt * 64 + n * 16 + ln);
                    int bswz = ((2 * n + (ln >> 3)) ^ quad) * 8 + (ln & 7);
                    #pragma unroll
                    for (int g = 0; g < 2; ++g) {
                        #pragma unroll
                        for (int r = 0; r < 4; ++r) {
                            float d = qrf[g][r] - kg;
                            float arg = fmaf(s[g][n][r], c1, -slope2 * fabsf(d));
                            float p = fexp2(arg);
                            Ps[w][g * 16 + quad * 4 + r][bswz] = (ushort)(fasu(p) >> 16);
                        }
                    }
                }
                // no barrier: Ps[w] is wave-private

                // O += P V ; lsum += P * ones
                #pragma unroll
                for (int hf = 0; hf < 2; ++hf) {
                    bf16x8 ap0 = as_bf8(*(const uint4*)&Ps[w][ln]     [((hf * 4 + quad) ^ (ln >> 2)) * 8]);
                    bf16x8 ap1 = as_bf8(*(const uint4*)&Ps[w][16 + ln][((hf * 4 + quad) ^ (ln >> 2)) * 8]);
                    #pragma unroll
                    for (int dn = 0; dn < 4; ++dn) {
                        bf16x8 bv = as_bf8(vf[dn * 2 + hf]);
                        o[0][dn] = __builtin_amdgcn_mfma_f32_16x16x32_bf16(ap0, bv, o[0][dn], 0, 0, 0);
                        o[1][dn] = __builtin_amdgcn_mfma_f32_16x16x32_bf16(ap1, bv, o[1][dn], 0, 0, 0);
                    }
                    lsum[0] = __builtin_amdgcn_mfma_f32_16x16x32_bf16(ap0, ones, lsum[0], 0, 0, 0);
                    lsum[1] = __builtin_amdgcn_mfma_f32_16x16x32_bf16(ap1, ones, lsum[1], 0, 0, 0);
                }

                #pragma unroll
                for (int i = 0; i < 8; ++i) kf[i] = kn[i];
            }
        }

        // -------- single-phase cross-wave merge --------
        __syncthreads();  // all loops done; Ps dead; Rbuf safe
        if (w > 0) {
            float* dst = &Rbuf[w - 1][lane][0];
            #pragma unroll
            for (int g = 0; g < 2; ++g) {
                #pragma unroll
                for (int dn = 0; dn < 4; ++dn)
                    #pragma unroll
                    for (int r = 0; r < 4; ++r)
                        dst[g * 16 + dn * 4 + r] = o[g][dn][r];
                #pragma unroll
                for (int r = 0; r < 4; ++r)
                    dst[32 + g * 4 + r] = lsum[g][r];
            }
        }
        __syncthreads();
        if (w == 0) {
            #pragma unroll
            for (int j = 0; j < 3; ++j) {
                const float* src = &Rbuf[j][lane][0];
                #pragma unroll
                for (int g = 0; g < 2; ++g) {
                    #pragma unroll
                    for (int dn = 0; dn < 4; ++dn)
                        #pragma unroll
                        for (int r = 0; r < 4; ++r)
                            o[g][dn][r] += src[g * 16 + dn * 4 + r];
                    #pragma unroll
                    for (int r = 0; r < 4; ++r)
                        lsum[g][r] += src[32 + g * 4 + r];
                }
            }
            // normalize, write [B][T][D] bf16
            #pragma unroll
            for (int g = 0; g < 2; ++g) {
                #pragma unroll
                for (int r = 0; r < 4; ++r) {
                    float inv = __builtin_amdgcn_rcpf(lsum[g][r]);
                    int q = qbase + g * 16 + quad * 4 + r;
                    size_t ob = ((size_t)(b * TT + q)) * DD + h * HD;
                    #pragma unroll
                    for (int dn = 0; dn < 4; ++dn)
                        outp[ob + dn * 16 + ln] = f2bf(o[g][dn][r] * inv);
                }
            }
        }

        // -------- grab next item (work stealing, heavy-first order) --------
        __syncthreads();  // w0's Rbuf reads done; LDS reusable
        if (tid == 0) s_item = atomicAdd(ctr, 1);
        __syncthreads();
        item = s_item;
    }
}

extern "C" void kernel_launch(void* const* d_in, const int* in_sizes, int n_in,
                              void* d_out, int out_size, void* d_ws, size_t ws_size,
                              hipStream_t stream) {
    const float* query = (const float*)d_in[0];
    const float* key   = (const float*)d_in[1];
    const float* value = (const float*)d_in[2];
    const float* Wq = (const float*)d_in[3];
    const float* bq = (const float*)d_in[4];
    const float* Wk = (const float*)d_in[5];
    const float* bk = (const float*)d_in[6];
    const float* Wv = (const float*)d_in[7];
    const float* bv = (const float*)d_in[8];
    const float* Wo = (const float*)d_in[9];
    const float* bo = (const float*)d_in[10];
    float* out = (float*)d_out;

    char* ws = (char*)d_ws;
    const size_t MB = 1024 * 1024;
    ushort* Xq  = (ushort*)(ws + 0);
    ushort* Xk  = (ushort*)(ws + 8 * MB);
    ushort* Xv  = (ushort*)(ws + 16 * MB);
    ushort* Wtq = (ushort*)(ws + 24 * MB);
    ushort* Wtk = (ushort*)(ws + 26 * MB);
    ushort* Wtv = (ushort*)(ws + 28 * MB);
    ushort* Wto = (ushort*)(ws + 30 * MB);
    ushort* Qh  = (ushort*)(ws + 32 * MB);
    ushort* Kh  = (ushort*)(ws + 40 * MB);
    ushort* Vt  = (ushort*)(ws + 48 * MB);  // written transposed by gemm z==2
    ushort* attn = (ushort*)(ws + 0);       // reuse Xq (free after QKV gemm)
    int* ctr = (int*)d_out;                 // d_out dead until final gemm overwrites

    // conversions + weight transpose + counter init, one launch
    prep<<<dim3(4096, 4), 256, 0, stream>>>(query, key, value, Wq, Wk, Wv, Wo,
                                            Xq, Xk, Xv, Wtq, Wtk, Wtv, Wto, ctr);

    // QKV projections: one z-batched launch; z==2 writes V transposed
    gemm_mfma<128, 0><<<dim3(8, 32, 3), 256, 0, stream>>>(
        Xq, Wtq, bq, Qh,  Xk, Wtk, bk, Kh,  Xv, Wtv, bv, Vt);

    // persistent-ish: 1024 blocks, dynamic work stealing over 2048 items
    attn_kernel<<<dim3(1024), 256, 0, stream>>>(Qh, Kh, Vt, attn, ctr);

    // output projection: 64x128 tiles, 512 blocks
    gemm_mfma<64, 1><<<dim3(8, 64, 1), 256, 0, stream>>>(
        attn, Wto, bo, out,  attn, Wto, bo, out,  attn, Wto, bo, out);
}